// Round 6
// baseline (105.041 us; speedup 1.0000x reference)
//
#include <hip/hip_runtime.h>
#include <math.h>

// TopologyHead: persistence image (B,64,64) + persistence landscapes (B,5,256)
// B=64, N=4096. Output = [image flat 262144][landscapes flat 81920], fp32.
//
// 2 graph nodes, no atomics:
//  k_partial (1024 blocks, role = blockIdx&1):
//    image (512): bf16-MFMA K-split GEMM (KC=8, 512 pts/block), scalar s_load
//                 point staging (wave-uniform offsets via readfirstlane).
//    land  (512): in-block batch minmax; each wave owns a 64-r window, 1 r
//                 per lane; per-point SCALAR support test (int bitcast cmp,
//                 all values >= 0) skips ~50% of work; med3 top-5 insert;
//                 waves store 5x64 segments straight to lp (no LDS merge).
//  k_finish (128 blocks): 64x image sum/max/normalize + 64x landscape merge
//                 of 8 partial lists per r.

#define B_   64
#define N_   4096
#define HW_  64
#define RES_ 256
#define EPSF 1e-8f
#define KC_  8          // image K-split (512 points per img block)
#define CPB  512        // points per image block
#define LPC_ 8          // landscape point-chunks per batch (512 pts each)

typedef short short8v  __attribute__((ext_vector_type(8)));
typedef float float4v  __attribute__((ext_vector_type(4)));

// pack two f32 -> bf16x2, round-half-up
__device__ __forceinline__ unsigned pk_bf(float a, float b) {
    unsigned ua = __float_as_uint(a), ub = __float_as_uint(b);
    return ((ua + 0x8000u) >> 16) | ((ub + 0x8000u) & 0xffff0000u);
}

// sorted-desc 5-list insert, 5 ops via med3; x<=0 is a no-op (list >= 0)
#define INS5(v0, v1, v2, v3, v4, x)                       \
    {                                                     \
        float _p0 = v0, _p1 = v1, _p2 = v2, _p3 = v3;     \
        v0 = fmaxf(_p0, x);                               \
        v1 = __builtin_amdgcn_fmed3f(_p0, _p1, x);        \
        v2 = __builtin_amdgcn_fmed3f(_p1, _p2, x);        \
        v3 = __builtin_amdgcn_fmed3f(_p2, _p3, x);        \
        v4 = __builtin_amdgcn_fmed3f(_p3, v4, x);         \
    }

union SmemU {
    struct {                                   // image path (18.4 KB)
        unsigned short gy[64 * 72];
        unsigned short gx[64 * 72];
    } img;
    struct {                                   // landscape path
        float red[8];
    } land;
};

__global__ __launch_bounds__(256) void k_partial(const float* __restrict__ pairs,
                                                 const float* __restrict__ sigp,
                                                 float* __restrict__ part,
                                                 float* __restrict__ lp) {
    __shared__ SmemU sm;
    int tid = threadIdx.x;
    int l = tid & 63;
    int w = __builtin_amdgcn_readfirstlane(tid >> 6);   // wave id, provably uniform
    int role = blockIdx.x & 1;
    int id   = blockIdx.x >> 1;                // 0..511

    if (role == 0) {
        // ================= image path =================
        int kc = id & 7, b = id >> 3;
        float sigma = sigp[0];
        float ncc2 = -(0.5f / (sigma * sigma)) * 1.4426950408889634f;

        int c = tid & 63;                      // coordinate this thread stages
        float xc = (float)c * (1.0f / 63.0f);

        float4v acc[4];
        #pragma unroll
        for (int c4 = 0; c4 < 4; ++c4) acc[c4] = (float4v){0.f, 0.f, 0.f, 0.f};

        int rowA = (w * 16 + (l & 15)) * 72 + (l >> 4) * 8;
        const float4* pb4 = (const float4*)(pairs + 2 * ((size_t)b * N_ + kc * CPB));

        for (int ch = 0; ch < CPB / 64; ++ch) {   // 8 chunks of 64 points
            // ---- stage 16 points/thread; offsets wave-uniform -> s_load ----
            int p0 = ch * 32 + w * 8;
            unsigned gxp[8], gyp[8];
            #pragma unroll
            for (int jp = 0; jp < 8; ++jp) {
                float4 q = pb4[p0 + jp];          // scalar load (uniform addr)
                float pe0 = q.y - q.x, pe1 = q.w - q.z;
                float dx0 = xc - q.x, dx1 = xc - q.z;
                float dy0 = xc - pe0, dy1 = xc - pe1;
                float ex0 = __builtin_amdgcn_exp2f(dx0 * dx0 * ncc2);
                float ex1 = __builtin_amdgcn_exp2f(dx1 * dx1 * ncc2);
                float ey0 = pe0 * __builtin_amdgcn_exp2f(dy0 * dy0 * ncc2);
                float ey1 = pe1 * __builtin_amdgcn_exp2f(dy1 * dy1 * ncc2);
                gxp[jp] = pk_bf(ex0, ex1);
                gyp[jp] = pk_bf(ey0, ey1);
            }
            __syncthreads();                      // prior MFMA reads done
            *(uint4*)&sm.img.gy[c * 72 + w * 16]     = *(uint4*)&gyp[0];
            *(uint4*)&sm.img.gy[c * 72 + w * 16 + 8] = *(uint4*)&gyp[4];
            *(uint4*)&sm.img.gx[c * 72 + w * 16]     = *(uint4*)&gxp[0];
            *(uint4*)&sm.img.gx[c * 72 + w * 16 + 8] = *(uint4*)&gxp[4];
            __syncthreads();
            // ---- MFMA: 2 k-steps of 32 points, 4 col-tiles each ----
            #pragma unroll
            for (int ks = 0; ks < 2; ++ks) {
                short8v af = *(const short8v*)&sm.img.gy[rowA + ks * 32];
                #pragma unroll
                for (int c4 = 0; c4 < 4; ++c4) {
                    short8v bf = *(const short8v*)
                        &sm.img.gx[(c4 * 16 + (l & 15)) * 72 + ks * 32 + (l >> 4) * 8];
                    acc[c4] = __builtin_amdgcn_mfma_f32_16x16x32_bf16(af, bf, acc[c4], 0, 0, 0);
                }
            }
        }

        // C/D layout: col=lane&15, row=(lane>>4)*4+reg
        float* dst = part + (size_t)(b * KC_ + kc) * (HW_ * HW_);
        #pragma unroll
        for (int c4 = 0; c4 < 4; ++c4)
            #pragma unroll
            for (int reg = 0; reg < 4; ++reg) {
                int h = w * 16 + (l >> 4) * 4 + reg;
                int wv = c4 * 16 + (l & 15);
                dst[h * HW_ + wv] = acc[c4][reg];
            }
    } else {
        // ================= landscape path =================
        int pc = id & 7, b = id >> 3;

        // ---- phase 0: in-block batch min/max (32 KB, L2-hot) ----
        const float4* pb4 = (const float4*)(pairs + 2 * (size_t)b * N_);
        float mn = 1e30f, mx = -1e30f;
        #pragma unroll
        for (int i = 0; i < 8; ++i) {
            float4 q = pb4[tid + i * 256];
            mn = fminf(mn, fminf(q.x, q.z));
            mx = fmaxf(mx, fmaxf(q.y, q.w));
        }
        #pragma unroll
        for (int off = 32; off > 0; off >>= 1) {
            mn = fminf(mn, __shfl_xor(mn, off, 64));
            mx = fmaxf(mx, __shfl_xor(mx, off, 64));
        }
        if ((tid & 63) == 0) { sm.land.red[w] = mn; sm.land.red[4 + w] = mx; }
        __syncthreads();
        float minb = fminf(fminf(sm.land.red[0], sm.land.red[1]),
                           fminf(sm.land.red[2], sm.land.red[3]));
        float maxd = fmaxf(fmaxf(sm.land.red[4], sm.land.red[5]),
                           fmaxf(sm.land.red[6], sm.land.red[7]));

        // ---- phase 1: wave w owns r-window [w*64, w*64+64); 1 r per lane ----
        float sc = (maxd - minb) * (1.0f / 255.0f);
        float t  = minb + sc * (float)(w * 64 + l);
        // window bounds for scalar support test (all values >= 0 -> int order)
        float tlo_f = minb + sc * (float)(w * 64);
        float thi_f = minb + sc * (float)(w * 64 + 63);
        int itlo = __builtin_amdgcn_readfirstlane(__float_as_int(tlo_f));
        int ithi = __builtin_amdgcn_readfirstlane(__float_as_int(thi_f));

        float v0 = 0.f, v1 = 0.f, v2 = 0.f, v3 = 0.f, v4 = 0.f;
        const float4* pw = (const float4*)(pairs + 2 * ((size_t)b * N_ + pc * 512));
        #pragma unroll 2
        for (int p = 0; p < 256; ++p) {
            float4 q = pw[p];                  // uniform addr -> s_load
            // point 0: support (b,d) vs window: skip iff d<=tlo or b>=thi
            if (__float_as_int(q.y) > itlo && __float_as_int(q.x) < ithi) {
                float x = fminf(t - q.x, q.y - t);
                INS5(v0, v1, v2, v3, v4, x);
            }
            if (__float_as_int(q.w) > itlo && __float_as_int(q.z) < ithi) {
                float x = fminf(t - q.z, q.w - t);
                INS5(v0, v1, v2, v3, v4, x);
            }
        }

        // store this wave's 5x64 segment: lp[((b*8+pc)*4 + w)*320 + lvl*64 + l]
        float* dl = lp + ((size_t)((b * LPC_ + pc) * 4 + w)) * 320;
        dl[0 * 64 + l] = v0;
        dl[1 * 64 + l] = v1;
        dl[2 * 64 + l] = v2;
        dl[3 * 64 + l] = v3;
        dl[4 * 64 + l] = v4;
    }
}

// ---------------- finish: image sum/max/normalize + landscape merge ----------------
__global__ __launch_bounds__(256) void k_finish(const float* __restrict__ part,
                                                const float* __restrict__ lp,
                                                float* __restrict__ out) {
    __shared__ float redf[4];
    int tid = threadIdx.x;
    if (blockIdx.x < 64) {
        int b = blockIdx.x;
        const float4* p0 = (const float4*)(part + (size_t)b * KC_ * (HW_ * HW_));
        float4 s[4];
        float m = 0.0f;
        #pragma unroll
        for (int i = 0; i < 4; ++i) {
            int pix4 = tid + i * 256;
            float4 v = p0[pix4];
            #pragma unroll
            for (int k2 = 1; k2 < KC_; ++k2) {
                float4 u = p0[(size_t)k2 * 1024 + pix4];
                v.x += u.x; v.y += u.y; v.z += u.z; v.w += u.w;
            }
            s[i] = v;
            m = fmaxf(m, fmaxf(fmaxf(v.x, v.y), fmaxf(v.z, v.w)));
        }
        #pragma unroll
        for (int off = 32; off > 0; off >>= 1) m = fmaxf(m, __shfl_xor(m, off, 64));
        if ((tid & 63) == 0) redf[tid >> 6] = m;
        __syncthreads();
        m = fmaxf(fmaxf(redf[0], redf[1]), fmaxf(redf[2], redf[3]));
        float inv = 1.0f / (m + EPSF);
        float4* od = (float4*)(out + (size_t)b * (HW_ * HW_));
        #pragma unroll
        for (int i = 0; i < 4; ++i) {
            float4 v = s[i];
            v.x *= inv; v.y *= inv; v.z *= inv; v.w *= inv;
            od[tid + i * 256] = v;
        }
    } else {
        // merge 8 partial lists for r = tid (window wq = tid>>6, lane = tid&63)
        int b = blockIdx.x - 64;
        int wq = tid >> 6, l = tid & 63;
        const float* lpb = lp + (size_t)b * (LPC_ * 4 * 320) + wq * 320 + l;
        float u0 = lpb[0 * 64], u1 = lpb[1 * 64], u2 = lpb[2 * 64],
              u3 = lpb[3 * 64], u4 = lpb[4 * 64];
        for (int p2 = 1; p2 < LPC_; ++p2) {
            const float* s2 = lpb + (size_t)p2 * 4 * 320;
            #pragma unroll
            for (int lvl = 0; lvl < 5; ++lvl) {
                float x = s2[lvl * 64];
                INS5(u0, u1, u2, u3, u4, x);
            }
        }
        float* o = out + (size_t)B_ * HW_ * HW_ + (size_t)b * (5 * RES_);
        o[tid]            = u0;
        o[RES_ + tid]     = u1;
        o[2 * RES_ + tid] = u2;
        o[3 * RES_ + tid] = u3;
        o[4 * RES_ + tid] = u4;
    }
}

extern "C" void kernel_launch(void* const* d_in, const int* in_sizes, int n_in,
                              void* d_out, int out_size, void* d_ws, size_t ws_size,
                              hipStream_t stream) {
    const float* pairs = (const float*)d_in[0];
    const float* sig   = (const float*)d_in[1];
    float* out = (float*)d_out;
    float* wsf = (float*)d_ws;

    // ws layout (floats): part (B*KC*4096 = 2M) | lp (B*8*4*320 = 655K)
    float* part = wsf;
    float* lp   = part + (size_t)B_ * KC_ * HW_ * HW_;

    k_partial<<<1024, 256, 0, stream>>>(pairs, sig, part, lp);
    k_finish<<<128, 256, 0, stream>>>(part, lp, out);
}

// Round 7
// 102.507 us; speedup vs baseline: 1.0247x; 1.0247x over previous
//
#include <hip/hip_runtime.h>
#include <math.h>

// TopologyHead: persistence image (B,64,64) + persistence landscapes (B,5,256)
// B=64, N=4096. Output = [image flat 262144][landscapes flat 81920], fp32.
//
// 3 graph nodes, no atomics:
//  k_minmax  (512): partial min-birth/max-death per (batch, octant) -> wsf
//  k_partial (2048, role=blockIdx&1): 8 blocks/CU = 32 waves/CU (HW max)
//    image (1024): bf16-MFMA K-split GEMM, KC=16 (256 pts/block)
//    land  (1024): LPC=16 (256 pts/block), wave owns 64-r window, 1 r/lane,
//                  BRANCHLESS med3 top-5 insert (R6's scalar branch test
//                  serialized on the SALU pipe — reverted)
//  k_finish  (128): 64x image sum(16)+max+normalize, 64x landscape merge(16)

#define B_   64
#define N_   4096
#define HW_  64
#define RES_ 256
#define EPSF 1e-8f
#define KC_  16         // image K-split (256 points per img block)
#define CPB  256        // points per image block
#define LPC_ 16         // landscape point-chunks per batch (256 pts each)

typedef short short8v  __attribute__((ext_vector_type(8)));
typedef float float4v  __attribute__((ext_vector_type(4)));

// pack two f32 -> bf16x2, round-half-up
__device__ __forceinline__ unsigned pk_bf(float a, float b) {
    unsigned ua = __float_as_uint(a), ub = __float_as_uint(b);
    return ((ua + 0x8000u) >> 16) | ((ub + 0x8000u) & 0xffff0000u);
}

// sorted-desc 5-list insert, 5 ops via med3; x<=0 is a no-op (list >= 0)
#define INS5(v0, v1, v2, v3, v4, x)                       \
    {                                                     \
        float _p0 = v0, _p1 = v1, _p2 = v2, _p3 = v3;     \
        v0 = fmaxf(_p0, x);                               \
        v1 = __builtin_amdgcn_fmed3f(_p0, _p1, x);        \
        v2 = __builtin_amdgcn_fmed3f(_p1, _p2, x);        \
        v3 = __builtin_amdgcn_fmed3f(_p2, _p3, x);        \
        v4 = __builtin_amdgcn_fmed3f(_p3, v4, x);         \
    }

union SmemU {
    struct {                                   // image path (18.4 KB)
        unsigned short gy[64 * 72];
        unsigned short gx[64 * 72];
    } img;
    struct {
        float red[8];
    } land;
};

// ---------------- kernel 1: partial min/max per (batch, octant) ----------------
__global__ __launch_bounds__(256) void k_minmax(const float* __restrict__ pairs,
                                                float* __restrict__ wsf) {
    int b = blockIdx.x >> 3, oct = blockIdx.x & 7, tid = threadIdx.x;
    // 512 points per octant: 256 float4 (2 pts each), 1 per thread
    const float4* pr = (const float4*)(pairs + 2 * ((size_t)b * N_ + oct * 512));
    float4 q = pr[tid];
    float mn = fminf(q.x, q.z);
    float mx = fmaxf(q.y, q.w);
    #pragma unroll
    for (int off = 32; off > 0; off >>= 1) {
        mn = fminf(mn, __shfl_xor(mn, off, 64));
        mx = fmaxf(mx, __shfl_xor(mx, off, 64));
    }
    __shared__ float smn[4], smx[4];
    if ((tid & 63) == 0) { smn[tid >> 6] = mn; smx[tid >> 6] = mx; }
    __syncthreads();
    if (tid == 0) {
        mn = fminf(fminf(smn[0], smn[1]), fminf(smn[2], smn[3]));
        mx = fmaxf(fmaxf(smx[0], smx[1]), fmaxf(smx[2], smx[3]));
        wsf[oct * 64 + b]       = mn;
        wsf[512 + oct * 64 + b] = mx;
    }
}

// ---------------- kernel 2: image MFMA partials + landscape partials ----------------
__global__ __launch_bounds__(256) void k_partial(const float* __restrict__ pairs,
                                                 const float* __restrict__ sigp,
                                                 const float* __restrict__ wsf,
                                                 float* __restrict__ part,
                                                 float* __restrict__ lp) {
    __shared__ SmemU sm;
    int tid = threadIdx.x;
    int l = tid & 63, w = tid >> 6;
    int role = blockIdx.x & 1;
    int id   = blockIdx.x >> 1;                // 0..1023

    if (role == 0) {
        // ================= image path =================
        int kc = id & 15, b = id >> 4;
        float sigma = sigp[0];
        float ncc2 = -(0.5f / (sigma * sigma)) * 1.4426950408889634f;

        int c = tid & 63;                      // coordinate this thread stages
        float xc = (float)c * (1.0f / 63.0f);

        float4v acc[4];
        #pragma unroll
        for (int c4 = 0; c4 < 4; ++c4) acc[c4] = (float4v){0.f, 0.f, 0.f, 0.f};

        int rowA = (w * 16 + (l & 15)) * 72 + (l >> 4) * 8;
        const float4* pb4 = (const float4*)(pairs + 2 * ((size_t)b * N_ + kc * CPB));

        for (int ch = 0; ch < CPB / 64; ++ch) {   // 4 chunks of 64 points
            // ---- stage: 16 points/thread (wave-uniform offsets) ----
            int p0 = ch * 32 + w * 8;
            unsigned gxp[8], gyp[8];
            #pragma unroll
            for (int jp = 0; jp < 8; ++jp) {
                float4 q = pb4[p0 + jp];
                float pe0 = q.y - q.x, pe1 = q.w - q.z;
                float dx0 = xc - q.x, dx1 = xc - q.z;
                float dy0 = xc - pe0, dy1 = xc - pe1;
                float ex0 = __builtin_amdgcn_exp2f(dx0 * dx0 * ncc2);
                float ex1 = __builtin_amdgcn_exp2f(dx1 * dx1 * ncc2);
                float ey0 = pe0 * __builtin_amdgcn_exp2f(dy0 * dy0 * ncc2);
                float ey1 = pe1 * __builtin_amdgcn_exp2f(dy1 * dy1 * ncc2);
                gxp[jp] = pk_bf(ex0, ex1);
                gyp[jp] = pk_bf(ey0, ey1);
            }
            __syncthreads();                      // prior MFMA reads done
            *(uint4*)&sm.img.gy[c * 72 + w * 16]     = *(uint4*)&gyp[0];
            *(uint4*)&sm.img.gy[c * 72 + w * 16 + 8] = *(uint4*)&gyp[4];
            *(uint4*)&sm.img.gx[c * 72 + w * 16]     = *(uint4*)&gxp[0];
            *(uint4*)&sm.img.gx[c * 72 + w * 16 + 8] = *(uint4*)&gxp[4];
            __syncthreads();
            // ---- MFMA: 2 k-steps of 32 points, 4 col-tiles each ----
            #pragma unroll
            for (int ks = 0; ks < 2; ++ks) {
                short8v af = *(const short8v*)&sm.img.gy[rowA + ks * 32];
                #pragma unroll
                for (int c4 = 0; c4 < 4; ++c4) {
                    short8v bf = *(const short8v*)
                        &sm.img.gx[(c4 * 16 + (l & 15)) * 72 + ks * 32 + (l >> 4) * 8];
                    acc[c4] = __builtin_amdgcn_mfma_f32_16x16x32_bf16(af, bf, acc[c4], 0, 0, 0);
                }
            }
        }

        // C/D layout: col=lane&15, row=(lane>>4)*4+reg
        float* dst = part + (size_t)(b * KC_ + kc) * (HW_ * HW_);
        #pragma unroll
        for (int c4 = 0; c4 < 4; ++c4)
            #pragma unroll
            for (int reg = 0; reg < 4; ++reg) {
                int h = w * 16 + (l >> 4) * 4 + reg;
                int wv = c4 * 16 + (l & 15);
                dst[h * HW_ + wv] = acc[c4][reg];
            }
    } else {
        // ================= landscape path =================
        int pc = id & 15, b = id >> 4;

        // reduce 8 partial min/max pairs (scalar, uniform)
        float minb = 1e30f, maxd = -1e30f;
        #pragma unroll
        for (int oct = 0; oct < 8; ++oct) {
            minb = fminf(minb, wsf[oct * 64 + b]);
            maxd = fmaxf(maxd, wsf[512 + oct * 64 + b]);
        }

        // wave w owns r-window [w*64, w*64+64); 1 r per lane
        float sc = (maxd - minb) * (1.0f / 255.0f);
        float t  = minb + sc * (float)(w * 64 + l);

        float v0 = 0.f, v1 = 0.f, v2 = 0.f, v3 = 0.f, v4 = 0.f;
        const float4* pw = (const float4*)(pairs + 2 * ((size_t)b * N_ + pc * CPB));
        #pragma unroll 4
        for (int p = 0; p < CPB / 2; ++p) {
            float4 q = pw[p];                  // wave-uniform addr, 2 points
            float x0 = fminf(t - q.x, q.y - t);
            INS5(v0, v1, v2, v3, v4, x0);
            float x1 = fminf(t - q.z, q.w - t);
            INS5(v0, v1, v2, v3, v4, x1);
        }

        // store wave's 5x64 segment: lp[((b*16+pc)*4 + w)*320 + lvl*64 + l]
        float* dl = lp + ((size_t)((b * LPC_ + pc) * 4 + w)) * 320;
        dl[0 * 64 + l] = v0;
        dl[1 * 64 + l] = v1;
        dl[2 * 64 + l] = v2;
        dl[3 * 64 + l] = v3;
        dl[4 * 64 + l] = v4;
    }
}

// ---------------- kernel 3: image finish + landscape merge ----------------
__global__ __launch_bounds__(256) void k_finish(const float* __restrict__ part,
                                                const float* __restrict__ lp,
                                                float* __restrict__ out) {
    __shared__ float redf[4];
    int tid = threadIdx.x;
    if (blockIdx.x < 64) {
        int b = blockIdx.x;
        const float4* p0 = (const float4*)(part + (size_t)b * KC_ * (HW_ * HW_));
        float4 s[4];
        float m = 0.0f;
        #pragma unroll
        for (int i = 0; i < 4; ++i) {
            int pix4 = tid + i * 256;
            float4 v = p0[pix4];
            #pragma unroll
            for (int k2 = 1; k2 < KC_; ++k2) {
                float4 u = p0[(size_t)k2 * 1024 + pix4];
                v.x += u.x; v.y += u.y; v.z += u.z; v.w += u.w;
            }
            s[i] = v;
            m = fmaxf(m, fmaxf(fmaxf(v.x, v.y), fmaxf(v.z, v.w)));
        }
        #pragma unroll
        for (int off = 32; off > 0; off >>= 1) m = fmaxf(m, __shfl_xor(m, off, 64));
        if ((tid & 63) == 0) redf[tid >> 6] = m;
        __syncthreads();
        m = fmaxf(fmaxf(redf[0], redf[1]), fmaxf(redf[2], redf[3]));
        float inv = 1.0f / (m + EPSF);
        float4* od = (float4*)(out + (size_t)b * (HW_ * HW_));
        #pragma unroll
        for (int i = 0; i < 4; ++i) {
            float4 v = s[i];
            v.x *= inv; v.y *= inv; v.z *= inv; v.w *= inv;
            od[tid + i * 256] = v;
        }
    } else {
        // merge 16 partial lists for r = tid (window wq = tid>>6, lane = tid&63)
        int b = blockIdx.x - 64;
        int wq = tid >> 6, l = tid & 63;
        const float* lpb = lp + (size_t)b * (LPC_ * 4 * 320) + wq * 320 + l;
        float u0 = lpb[0 * 64], u1 = lpb[1 * 64], u2 = lpb[2 * 64],
              u3 = lpb[3 * 64], u4 = lpb[4 * 64];
        for (int p2 = 1; p2 < LPC_; ++p2) {
            const float* s2 = lpb + (size_t)p2 * 4 * 320;
            #pragma unroll
            for (int lvl = 0; lvl < 5; ++lvl) {
                float x = s2[lvl * 64];
                INS5(u0, u1, u2, u3, u4, x);
            }
        }
        float* o = out + (size_t)B_ * HW_ * HW_ + (size_t)b * (5 * RES_);
        o[tid]            = u0;
        o[RES_ + tid]     = u1;
        o[2 * RES_ + tid] = u2;
        o[3 * RES_ + tid] = u3;
        o[4 * RES_ + tid] = u4;
    }
}

extern "C" void kernel_launch(void* const* d_in, const int* in_sizes, int n_in,
                              void* d_out, int out_size, void* d_ws, size_t ws_size,
                              hipStream_t stream) {
    const float* pairs = (const float*)d_in[0];
    const float* sig   = (const float*)d_in[1];
    float* out = (float*)d_out;
    float* wsf = (float*)d_ws;

    // ws layout (floats): [0..1023] partial min/max | part (B*16*4096 = 4M) |
    //                     lp (B*16*4*320 = 1.31M)
    float* part = wsf + 1024;
    float* lp   = part + (size_t)B_ * KC_ * HW_ * HW_;

    k_minmax<<<512, 256, 0, stream>>>(pairs, wsf);
    k_partial<<<2048, 256, 0, stream>>>(pairs, sig, wsf, part, lp);
    k_finish<<<128, 256, 0, stream>>>(part, lp, out);
}

// Round 8
// 99.109 us; speedup vs baseline: 1.0599x; 1.0343x over previous
//
#include <hip/hip_runtime.h>
#include <math.h>

// TopologyHead: persistence image (B,64,64) + persistence landscapes (B,5,256)
// B=64, N=4096. Output = [image flat 262144][landscapes flat 81920], fp32.
//
// 2 graph nodes, no atomics:
//  k_partial (2048 blocks, role=(blockIdx>>3)&1 so roles mix within XCDs):
//    image (1024): bf16-MFMA K-split GEMM, KC=16 (256 pts/block). Points
//                  staged to LDS once (coalesced); stage loop reads LDS
//                  broadcast (R5-R7 read global per-lane uniform -> serial
//                  L2 latency; that was the stall).
//    land  (1024): LPC=16 (256 pts/block): in-block full-batch minmax scan
//                  (coalesced, L2-hot), then tents from LDS-staged chunk,
//                  branchless med3 top-5 insert, 1 r/lane per 64-r window.
//  k_finish  (128): 64x image sum(16)+max+normalize, 64x landscape merge(16).

#define B_   64
#define N_   4096
#define HW_  64
#define RES_ 256
#define EPSF 1e-8f
#define KC_  16         // image K-split (256 points per img block)
#define CPB  256        // points per block (both roles)
#define LPC_ 16         // landscape point-chunks per batch

typedef short short8v  __attribute__((ext_vector_type(8)));
typedef float float4v  __attribute__((ext_vector_type(4)));

// pack two f32 -> bf16x2, round-half-up
__device__ __forceinline__ unsigned pk_bf(float a, float b) {
    unsigned ua = __float_as_uint(a), ub = __float_as_uint(b);
    return ((ua + 0x8000u) >> 16) | ((ub + 0x8000u) & 0xffff0000u);
}

// sorted-desc 5-list insert, 5 ops via med3; x<=0 is a no-op (list >= 0)
#define INS5(v0, v1, v2, v3, v4, x)                       \
    {                                                     \
        float _p0 = v0, _p1 = v1, _p2 = v2, _p3 = v3;     \
        v0 = fmaxf(_p0, x);                               \
        v1 = __builtin_amdgcn_fmed3f(_p0, _p1, x);        \
        v2 = __builtin_amdgcn_fmed3f(_p1, _p2, x);        \
        v3 = __builtin_amdgcn_fmed3f(_p2, _p3, x);        \
        v4 = __builtin_amdgcn_fmed3f(_p3, v4, x);         \
    }

union SmemU {                                  // 18432 B
    struct { unsigned short gy[64 * 72]; unsigned short gx[64 * 72]; } img;
    struct { float red[8]; } land;
};

__global__ __launch_bounds__(256) void k_partial(const float* __restrict__ pairs,
                                                 const float* __restrict__ sigp,
                                                 float* __restrict__ part,
                                                 float* __restrict__ lp) {
    __shared__ SmemU sm;
    __shared__ float4 ptsS[128];               // 2 KB: this block's 256 points
    int tid = threadIdx.x;
    int l = tid & 63, w = tid >> 6;
    unsigned g = blockIdx.x;
    int role = (g >> 3) & 1;
    int id   = (int)(((g >> 4) << 3) | (g & 7));   // 0..1023, bijective

    int sub = id & 15, b = id >> 4;            // kc or pc, batch

    // ---- stage this block's 2 KB point chunk to LDS (coalesced burst) ----
    const float4* src = (const float4*)(pairs + 2 * ((size_t)b * N_ + sub * CPB));
    if (tid < 128) ptsS[tid] = src[tid];

    if (role == 0) {
        // ================= image path =================
        float sigma = sigp[0];
        float ncc2 = -(0.5f / (sigma * sigma)) * 1.4426950408889634f;

        int c = tid & 63;                      // coordinate this thread stages
        float xc = (float)c * (1.0f / 63.0f);

        float4v acc[4];
        #pragma unroll
        for (int c4 = 0; c4 < 4; ++c4) acc[c4] = (float4v){0.f, 0.f, 0.f, 0.f};

        int rowA = (w * 16 + (l & 15)) * 72 + (l >> 4) * 8;
        __syncthreads();                       // ptsS ready

        for (int ch = 0; ch < CPB / 64; ++ch) {   // 4 chunks of 64 points
            // ---- stage: 16 points/thread from LDS broadcast ----
            int p0 = ch * 32 + w * 8;
            unsigned gxp[8], gyp[8];
            #pragma unroll
            for (int jp = 0; jp < 8; ++jp) {
                float4 q = ptsS[p0 + jp];         // ds_read_b128 broadcast
                float pe0 = q.y - q.x, pe1 = q.w - q.z;
                float dx0 = xc - q.x, dx1 = xc - q.z;
                float dy0 = xc - pe0, dy1 = xc - pe1;
                float ex0 = __builtin_amdgcn_exp2f(dx0 * dx0 * ncc2);
                float ex1 = __builtin_amdgcn_exp2f(dx1 * dx1 * ncc2);
                float ey0 = pe0 * __builtin_amdgcn_exp2f(dy0 * dy0 * ncc2);
                float ey1 = pe1 * __builtin_amdgcn_exp2f(dy1 * dy1 * ncc2);
                gxp[jp] = pk_bf(ex0, ex1);
                gyp[jp] = pk_bf(ey0, ey1);
            }
            __syncthreads();                      // prior MFMA reads done
            *(uint4*)&sm.img.gy[c * 72 + w * 16]     = *(uint4*)&gyp[0];
            *(uint4*)&sm.img.gy[c * 72 + w * 16 + 8] = *(uint4*)&gyp[4];
            *(uint4*)&sm.img.gx[c * 72 + w * 16]     = *(uint4*)&gxp[0];
            *(uint4*)&sm.img.gx[c * 72 + w * 16 + 8] = *(uint4*)&gxp[4];
            __syncthreads();
            // ---- MFMA: 2 k-steps of 32 points, 4 col-tiles each ----
            #pragma unroll
            for (int ks = 0; ks < 2; ++ks) {
                short8v af = *(const short8v*)&sm.img.gy[rowA + ks * 32];
                #pragma unroll
                for (int c4 = 0; c4 < 4; ++c4) {
                    short8v bf = *(const short8v*)
                        &sm.img.gx[(c4 * 16 + (l & 15)) * 72 + ks * 32 + (l >> 4) * 8];
                    acc[c4] = __builtin_amdgcn_mfma_f32_16x16x32_bf16(af, bf, acc[c4], 0, 0, 0);
                }
            }
        }

        // C/D layout: col=lane&15, row=(lane>>4)*4+reg
        float* dst = part + (size_t)(b * KC_ + sub) * (HW_ * HW_);
        #pragma unroll
        for (int c4 = 0; c4 < 4; ++c4)
            #pragma unroll
            for (int reg = 0; reg < 4; ++reg) {
                int h = w * 16 + (l >> 4) * 4 + reg;
                int wv = c4 * 16 + (l & 15);
                dst[h * HW_ + wv] = acc[c4][reg];
            }
    } else {
        // ================= landscape path =================
        // ---- in-block full-batch min/max (32 KB coalesced, L2-hot) ----
        const float4* pb4 = (const float4*)(pairs + 2 * (size_t)b * N_);
        float mn = 1e30f, mx = -1e30f;
        #pragma unroll
        for (int i = 0; i < 8; ++i) {
            float4 q = pb4[tid + i * 256];
            mn = fminf(mn, fminf(q.x, q.z));
            mx = fmaxf(mx, fmaxf(q.y, q.w));
        }
        #pragma unroll
        for (int off = 32; off > 0; off >>= 1) {
            mn = fminf(mn, __shfl_xor(mn, off, 64));
            mx = fmaxf(mx, __shfl_xor(mx, off, 64));
        }
        if ((tid & 63) == 0) { sm.land.red[w] = mn; sm.land.red[4 + w] = mx; }
        __syncthreads();                       // ptsS + red ready
        float minb = fminf(fminf(sm.land.red[0], sm.land.red[1]),
                           fminf(sm.land.red[2], sm.land.red[3]));
        float maxd = fmaxf(fmaxf(sm.land.red[4], sm.land.red[5]),
                           fmaxf(sm.land.red[6], sm.land.red[7]));

        // wave w owns r-window [w*64, w*64+64); 1 r per lane
        float sc = (maxd - minb) * (1.0f / 255.0f);
        float t  = minb + sc * (float)(w * 64 + l);

        float v0 = 0.f, v1 = 0.f, v2 = 0.f, v3 = 0.f, v4 = 0.f;
        #pragma unroll 4
        for (int p = 0; p < CPB / 2; ++p) {
            float4 q = ptsS[p];                // ds_read_b128 broadcast, 2 pts
            float x0 = fminf(t - q.x, q.y - t);
            INS5(v0, v1, v2, v3, v4, x0);
            float x1 = fminf(t - q.z, q.w - t);
            INS5(v0, v1, v2, v3, v4, x1);
        }

        // store wave's 5x64 segment: lp[((b*16+pc)*4 + w)*320 + lvl*64 + l]
        float* dl = lp + ((size_t)((b * LPC_ + sub) * 4 + w)) * 320;
        dl[0 * 64 + l] = v0;
        dl[1 * 64 + l] = v1;
        dl[2 * 64 + l] = v2;
        dl[3 * 64 + l] = v3;
        dl[4 * 64 + l] = v4;
    }
}

// ---------------- kernel 2: image finish + landscape merge ----------------
__global__ __launch_bounds__(256) void k_finish(const float* __restrict__ part,
                                                const float* __restrict__ lp,
                                                float* __restrict__ out) {
    __shared__ float redf[4];
    int tid = threadIdx.x;
    if (blockIdx.x < 64) {
        int b = blockIdx.x;
        const float4* p0 = (const float4*)(part + (size_t)b * KC_ * (HW_ * HW_));
        float4 s[4];
        float m = 0.0f;
        #pragma unroll
        for (int i = 0; i < 4; ++i) {
            int pix4 = tid + i * 256;
            float4 v = p0[pix4];
            #pragma unroll
            for (int k2 = 1; k2 < KC_; ++k2) {
                float4 u = p0[(size_t)k2 * 1024 + pix4];
                v.x += u.x; v.y += u.y; v.z += u.z; v.w += u.w;
            }
            s[i] = v;
            m = fmaxf(m, fmaxf(fmaxf(v.x, v.y), fmaxf(v.z, v.w)));
        }
        #pragma unroll
        for (int off = 32; off > 0; off >>= 1) m = fmaxf(m, __shfl_xor(m, off, 64));
        if ((tid & 63) == 0) redf[tid >> 6] = m;
        __syncthreads();
        m = fmaxf(fmaxf(redf[0], redf[1]), fmaxf(redf[2], redf[3]));
        float inv = 1.0f / (m + EPSF);
        float4* od = (float4*)(out + (size_t)b * (HW_ * HW_));
        #pragma unroll
        for (int i = 0; i < 4; ++i) {
            float4 v = s[i];
            v.x *= inv; v.y *= inv; v.z *= inv; v.w *= inv;
            od[tid + i * 256] = v;
        }
    } else {
        // merge 16 partial lists for r = tid (window wq = tid>>6, lane = tid&63)
        int b = blockIdx.x - 64;
        int wq = tid >> 6, l = tid & 63;
        const float* lpb = lp + (size_t)b * (LPC_ * 4 * 320) + wq * 320 + l;
        float u0 = lpb[0 * 64], u1 = lpb[1 * 64], u2 = lpb[2 * 64],
              u3 = lpb[3 * 64], u4 = lpb[4 * 64];
        for (int p2 = 1; p2 < LPC_; ++p2) {
            const float* s2 = lpb + (size_t)p2 * 4 * 320;
            #pragma unroll
            for (int lvl = 0; lvl < 5; ++lvl) {
                float x = s2[lvl * 64];
                INS5(u0, u1, u2, u3, u4, x);
            }
        }
        float* o = out + (size_t)B_ * HW_ * HW_ + (size_t)b * (5 * RES_);
        o[tid]            = u0;
        o[RES_ + tid]     = u1;
        o[2 * RES_ + tid] = u2;
        o[3 * RES_ + tid] = u3;
        o[4 * RES_ + tid] = u4;
    }
}

extern "C" void kernel_launch(void* const* d_in, const int* in_sizes, int n_in,
                              void* d_out, int out_size, void* d_ws, size_t ws_size,
                              hipStream_t stream) {
    const float* pairs = (const float*)d_in[0];
    const float* sig   = (const float*)d_in[1];
    float* out = (float*)d_out;
    float* wsf = (float*)d_ws;

    // ws layout (floats): part (B*16*4096 = 4M) | lp (B*16*4*320 = 1.31M)
    float* part = wsf;
    float* lp   = part + (size_t)B_ * KC_ * HW_ * HW_;

    k_partial<<<2048, 256, 0, stream>>>(pairs, sig, part, lp);
    k_finish<<<128, 256, 0, stream>>>(part, lp, out);
}